// Round 4
// baseline (718.019 us; speedup 1.0000x reference)
//
#include <hip/hip_runtime.h>
#include <math.h>

#define NC    30
#define D     300
#define WIN   100
#define TOPK  25
#define NEGV  -1e10f
#define TTOK  8              // tokens per staged LDS tile

#if defined(__has_builtin)
#if __has_builtin(__builtin_amdgcn_global_load_lds)
#define HAVE_DMA 1
#endif
#endif

__global__ __launch_bounds__(256, 3)
void fused_mention_kernel(const float* __restrict__ E,
                          const float* __restrict__ T,
                          const void*  __restrict__ maskp,
                          const float* __restrict__ B1,
                          const float* __restrict__ B2,
                          float* __restrict__ out)
{
    const int n    = blockIdx.x;
    const int tid  = threadIdx.x;
    const int dg   = tid >> 5;        // 0..7  d-slice group
    const int cg   = tid & 31;        // 0..31 candidate (30 real + 2 pad)
    const int wv   = tid >> 6;        // wave id 0..3
    const int lane = tid & 63;
    const int d0   = dg * 40;         // groups 0..6: 40 floats; group 7: 20
    const bool cok  = (cg < NC);
    const bool full = (dg < 7);
    const float cmask = cok ? 1.f : 0.f;

    __shared__ float Ttile[2][TTOK * D];           // 19.2 KB double-buffered T tile
    __shared__ float part[2][4][32][TTOK + 1];     // 9.2 KB double-buffered partials
    __shared__ float ts[WIN];
    __shared__ float bscore[TOPK];
    __shared__ int   bidx[TOPK];
    __shared__ float bprob[TOPK];
    __shared__ float vred[4][32];
    __shared__ int   mmode;
    __shared__ int   lcnt[2];

    // ---- mask dtype detect + ts init ----
    if (tid == 0) mmode = 0;
    if (tid < WIN) ts[tid] = NEGV;
    __syncthreads();
    {
        const unsigned char* mb = (const unsigned char*)maskp;
        int found = 0;
        for (int i = tid; i < 4096; i += 256)
            if ((i & 3) && mb[i]) found = 1;
        if (found) mmode = 1;
    }
    __syncthreads();

    // ---- valid-prefix length L via 2-wave ballot ----
    if (tid < 128) {
        int v = 0;
        if (tid < WIN) {
            if (mmode) v = ((const unsigned char*)maskp)[(size_t)n * WIN + tid] != 0;
            else       v = ((const int*)maskp)[(size_t)n * WIN + tid] != 0;
        }
        unsigned long long b = __ballot(v);
        if (lane == 0) lcnt[wv] = __popcll(b);
    }

    const float* Tn = T + (size_t)n * WIN * D;

    // ---- stage tile 0 (DMA, overlaps E load below) ----
#ifdef HAVE_DMA
    {
        const int nf4 = TTOK * (D / 4);   // tile 0 always full (WIN >= 8)
        const float* g = Tn;
        float* dst = &Ttile[0][0];
        for (int i = tid; i < nf4; i += 256) {
            __builtin_amdgcn_global_load_lds(
                (const __attribute__((address_space(1))) void*)(g + 4 * i),
                (__attribute__((address_space(3))) void*)(dst + 4 * i),
                16, 0, 0);
        }
    }
#else
    {
        const int nf4 = TTOK * (D / 4);
        const float* g = Tn;
        for (int i = tid; i < nf4; i += 256)
            *reinterpret_cast<float4*>(&Ttile[0][4 * i]) =
                *reinterpret_cast<const float4*>(g + 4 * i);
    }
#endif

    // ---- E slice -> registers, fold B_diag2 ----
    float4 e[10];
    {
        const float* Erow = E + ((size_t)n * NC + (cok ? cg : 0)) * D + d0;
        float4 ev[10], bv[10];
        #pragma unroll
        for (int j = 0; j < 5; ++j) {
            ev[j] = *reinterpret_cast<const float4*>(Erow + 4 * j);
            bv[j] = *reinterpret_cast<const float4*>(B2 + d0 + 4 * j);
        }
        if (full) {
            #pragma unroll
            for (int j = 5; j < 10; ++j) {
                ev[j] = *reinterpret_cast<const float4*>(Erow + 4 * j);
                bv[j] = *reinterpret_cast<const float4*>(B2 + d0 + 4 * j);
            }
        } else {
            #pragma unroll
            for (int j = 5; j < 10; ++j) {
                ev[j] = make_float4(0.f, 0.f, 0.f, 0.f);
                bv[j] = make_float4(0.f, 0.f, 0.f, 0.f);
            }
        }
        #pragma unroll
        for (int j = 0; j < 10; ++j) {
            e[j].x = ev[j].x * bv[j].x * cmask;
            e[j].y = ev[j].y * bv[j].y * cmask;
            e[j].z = ev[j].z * bv[j].z * cmask;
            e[j].w = ev[j].w * bv[j].w * cmask;
        }
    }

    __syncthreads();                       // lcnt ready + tile 0 DMA drained
    const int L = lcnt[0] + lcnt[1];
    const int ntiles = (L + TTOK - 1) / TTOK;

    // ---- main tiled score loop: 1 barrier per tile ----
    int cur = 0;
    for (int t = 0; t < ntiles; ++t) {
        const int t0 = t * TTOK;
        const int pb = t & 1;
        // issue next tile's DMA into the other buffer
        if (t + 1 < ntiles) {
            const int t1 = t0 + TTOK;
            const int rows = min(TTOK, L - t1);
            const int nf4 = rows * (D / 4);
            const float* g = Tn + (size_t)t1 * D;
            float* dst = &Ttile[cur ^ 1][0];
#ifdef HAVE_DMA
            for (int i = tid; i < nf4; i += 256) {
                __builtin_amdgcn_global_load_lds(
                    (const __attribute__((address_space(1))) void*)(g + 4 * i),
                    (__attribute__((address_space(3))) void*)(dst + 4 * i),
                    16, 0, 0);
            }
#else
            for (int i = tid; i < nf4; i += 256)
                *reinterpret_cast<float4*>(dst + 4 * i) =
                    *reinterpret_cast<const float4*>(g + 4 * i);
#endif
        }
        // score all 8 tokens (branch-free; tail tokens produce unused garbage)
        const float* Tl = &Ttile[cur][0];
        #pragma unroll
        for (int w8 = 0; w8 < TTOK; ++w8) {
            const float* Trow = Tl + w8 * D + d0;
            float4 tt[10];
            #pragma unroll
            for (int j = 0; j < 5; ++j)
                tt[j] = *reinterpret_cast<const float4*>(Trow + 4 * j);
            if (full) {
                #pragma unroll
                for (int j = 5; j < 10; ++j)
                    tt[j] = *reinterpret_cast<const float4*>(Trow + 4 * j);
            }
            float a0 = 0.f, a1 = 0.f;
            #pragma unroll
            for (int j = 0; j < 5; ++j) {
                float v = e[j].x * tt[j].x + e[j].y * tt[j].y
                        + e[j].z * tt[j].z + e[j].w * tt[j].w;
                if (j & 1) a1 += v; else a0 += v;
            }
            if (full) {
                #pragma unroll
                for (int j = 5; j < 10; ++j) {
                    float v = e[j].x * tt[j].x + e[j].y * tt[j].y
                            + e[j].z * tt[j].z + e[j].w * tt[j].w;
                    if (j & 1) a1 += v; else a0 += v;
                }
            }
            float acc = a0 + a1;
            acc += __shfl_xor(acc, 32);
            if (lane < 32) part[pb][wv][cg][w8] = acc;
        }
        __syncthreads();                   // part visible; next tile's DMA drained
        // per-tile token max over candidates (reads part[pb]; next tile writes part[pb^1])
        {
            const int w8   = tid >> 5;
            const int c    = tid & 31;
            const int wcnt = min(TTOK, L - t0);
            if (w8 < wcnt) {
                float s = ((part[pb][0][c][w8] + part[pb][1][c][w8])
                          + part[pb][2][c][w8]) + part[pb][3][c][w8];
                if (c >= NC) s = -__builtin_inff();
                #pragma unroll
                for (int m = 16; m >= 1; m >>= 1)
                    s = fmaxf(s, __shfl_xor(s, m));
                if (c == 0) ts[t0 + w8] = s;
            }
        }
        cur ^= 1;
    }
    __syncthreads();                       // ts complete

    // ---- top-25 (wave 0, lower-index tie-break) + double-normalized softmax ----
    if (tid < 64) {
        float va = ts[tid];
        float vb = (tid + 64 < WIN) ? ts[tid + 64] : -__builtin_inff();
        float mx = 0.f;
        for (int t = 0; t < TOPK; ++t) {
            float v0; int i0;
            if (vb > va) { v0 = vb; i0 = tid + 64; } else { v0 = va; i0 = tid; }
            #pragma unroll
            for (int s = 32; s >= 1; s >>= 1) {
                float ov = __shfl_xor(v0, s);
                int   oi = __shfl_xor(i0, s);
                if (ov > v0 || (ov == v0 && oi < i0)) { v0 = ov; i0 = oi; }
            }
            if (t == 0) mx = v0;
            if (tid == 0) { bscore[t] = v0; bidx[t] = i0; }
            if (i0 == tid) va = -__builtin_inff();
            else if (i0 == tid + 64) vb = -__builtin_inff();
        }
        float sc = (tid < TOPK) ? bscore[tid] : 0.f;
        float p  = (tid < TOPK) ? expf(sc - mx) : 0.f;
        float s1 = p;
        #pragma unroll
        for (int s = 32; s >= 1; s >>= 1) s1 += __shfl_xor(s1, s);
        p = p / s1;
        float s2 = p;   // reference renormalizes a second time
        #pragma unroll
        for (int s = 32; s >= 1; s >>= 1) s2 += __shfl_xor(s2, s);
        p = p / s2;
        if (tid < TOPK) bprob[tid] = p;
    }
    __syncthreads();

    // ---- fcs: probability-weighted sum of best tokens (rows are L2/L3 hot) ----
    float4 fc[10];
    #pragma unroll
    for (int j = 0; j < 10; ++j) fc[j] = make_float4(0.f, 0.f, 0.f, 0.f);
    for (int t = 0; t < TOPK; ++t) {
        const float p = bprob[t];
        const float* Trow = Tn + (size_t)bidx[t] * D + d0;
        float4 tt[10];
        #pragma unroll
        for (int j = 0; j < 5; ++j)
            tt[j] = *reinterpret_cast<const float4*>(Trow + 4 * j);
        if (full) {
            #pragma unroll
            for (int j = 5; j < 10; ++j)
                tt[j] = *reinterpret_cast<const float4*>(Trow + 4 * j);
        }
        #pragma unroll
        for (int j = 0; j < 5; ++j) {
            fc[j].x += p * tt[j].x; fc[j].y += p * tt[j].y;
            fc[j].z += p * tt[j].z; fc[j].w += p * tt[j].w;
        }
        if (full) {
            #pragma unroll
            for (int j = 5; j < 10; ++j) {
                fc[j].x += p * tt[j].x; fc[j].y += p * tt[j].y;
                fc[j].z += p * tt[j].z; fc[j].w += p * tt[j].w;
            }
        }
    }

    // ---- vals[c] = sum_d E_raw[c,d] * B1[d] * fcs[d] (E re-read, L3-hot) ----
    float acc2 = 0.f;
    {
        const float* Erow = E + ((size_t)n * NC + (cok ? cg : 0)) * D + d0;
        float4 ev[10], bv[10];
        #pragma unroll
        for (int j = 0; j < 5; ++j) {
            ev[j] = *reinterpret_cast<const float4*>(Erow + 4 * j);
            bv[j] = *reinterpret_cast<const float4*>(B1 + d0 + 4 * j);
        }
        if (full) {
            #pragma unroll
            for (int j = 5; j < 10; ++j) {
                ev[j] = *reinterpret_cast<const float4*>(Erow + 4 * j);
                bv[j] = *reinterpret_cast<const float4*>(B1 + d0 + 4 * j);
            }
        } else {
            #pragma unroll
            for (int j = 5; j < 10; ++j) {
                ev[j] = make_float4(0.f, 0.f, 0.f, 0.f);
                bv[j] = make_float4(0.f, 0.f, 0.f, 0.f);
            }
        }
        #pragma unroll
        for (int j = 0; j < 10; ++j) {
            acc2 += ev[j].x * bv[j].x * fc[j].x + ev[j].y * bv[j].y * fc[j].y
                  + ev[j].z * bv[j].z * fc[j].z + ev[j].w * bv[j].w * fc[j].w;
        }
    }
    acc2 *= cmask;
    acc2 += __shfl_xor(acc2, 32);
    if (lane < 32) vred[wv][cg] = acc2;
    __syncthreads();
    if (tid < NC) {
        out[(size_t)n * NC + tid] =
            vred[0][tid] + vred[1][tid] + vred[2][tid] + vred[3][tid];
    }
}

extern "C" void kernel_launch(void* const* d_in, const int* in_sizes, int n_in,
                              void* d_out, int out_size, void* d_ws, size_t ws_size,
                              hipStream_t stream)
{
    const float* E  = (const float*)d_in[0];
    const float* T  = (const float*)d_in[1];
    const void*  M  = d_in[2];
    const float* B1 = (const float*)d_in[3];
    const float* B2 = (const float*)d_in[4];
    float* out = (float*)d_out;
    const int n = in_sizes[0] / (NC * D);   // number of mentions
    fused_mention_kernel<<<n, 256, 0, stream>>>(E, T, M, B1, B2, out);
}

// Round 5
// 551.668 us; speedup vs baseline: 1.3015x; 1.3015x over previous
//
#include <hip/hip_runtime.h>
#include <math.h>

#define NC    30
#define D     300
#define WIN   100
#define TOPK  25
#define NEGV  -1e10f
#define KP    308          // padded K stride for LDS T tile (f32), %4==0
#define NKS   19           // MFMA k-steps: 19*16 = 304 >= 300

typedef __attribute__((ext_vector_type(8)))  short short8;
typedef __attribute__((ext_vector_type(16))) float f32x16;

__device__ inline unsigned short bftrunc(float f) {
    return (unsigned short)(__builtin_bit_cast(unsigned int, f) >> 16);
}
__device__ inline float bfval(unsigned short b) {
    return __builtin_bit_cast(float, (unsigned int)b << 16);
}
// split 8 f32 into bf16 hi/lo planes (a ~= hi + lo, |resid| ~ 2^-18 |a|)
__device__ inline void split8(const float* v, short8& hi, short8& lo) {
    #pragma unroll
    for (int j = 0; j < 8; ++j) {
        unsigned short hb = bftrunc(v[j]);
        float lf = v[j] - bfval(hb);
        hi[j] = (short)hb;
        lo[j] = (short)bftrunc(lf);
    }
}

__global__ __launch_bounds__(256, 3)
void fused_mention_kernel(const float* __restrict__ E,
                          const float* __restrict__ T,
                          const void*  __restrict__ maskp,
                          const float* __restrict__ B1,
                          const float* __restrict__ B2,
                          const float* __restrict__ zws,
                          float* __restrict__ out)
{
    const int n    = blockIdx.x;
    const int tid  = threadIdx.x;
    const int dg   = tid >> 5;        // 0..7 d-slice group (fcs/vals phases)
    const int wv   = tid >> 6;        // wave id 0..3
    const int lane = tid & 63;
    const int d0   = dg * 40;
    const bool full = (dg < 7);

    __shared__ float Tl[32 * KP];            // 39.4 KB: one 32-token tile, f32
    __shared__ float Cred[3][8][32][4];      // 12.3 KB: cross-wave C partials
    __shared__ float ts[WIN];
    __shared__ float bscore[TOPK];
    __shared__ int   bidx[TOPK];
    __shared__ float bprob[TOPK];
    __shared__ float vred[4][32];
    __shared__ int   mmode;
    __shared__ int   lcnt[2];

    // ---- mask dtype detect + ts init ----
    if (tid == 0) mmode = 0;
    if (tid < WIN) ts[tid] = NEGV;
    __syncthreads();
    {
        const unsigned char* mb = (const unsigned char*)maskp;
        int found = 0;
        for (int i = tid; i < 4096; i += 256)
            if ((i & 3) && mb[i]) found = 1;
        if (found) mmode = 1;
    }
    __syncthreads();

    // ---- valid-prefix length L via 2-wave ballot ----
    if (tid < 128) {
        int v = 0;
        if (tid < WIN) {
            if (mmode) v = ((const unsigned char*)maskp)[(size_t)n * WIN + tid] != 0;
            else       v = ((const int*)maskp)[(size_t)n * WIN + tid] != 0;
        }
        unsigned long long b = __ballot(v);
        if (lane == 0) lcnt[wv] = __popcll(b);
    }

    // ---- A-fragments (E, bf16 split) into registers; waves split K ----
    // A layout (32x32x16): lane holds A[row = l&31][kb .. kb+8), kb = 16*s + 8*(l>>5)
    const int ks0 = wv * 5;                        // waves 0-2: 5 steps, wave 3: 4
    const int arow = lane & 31;
    const int khalf = (lane >> 5) * 8;
    short8 ah[5], al[5];
    #pragma unroll
    for (int s5 = 0; s5 < 5; ++s5) {
        int s = ks0 + s5;
        float v[8];
        #pragma unroll
        for (int j = 0; j < 8; ++j) v[j] = 0.f;
        if (s < NKS && arow < NC) {
            const int kb = 16 * s + khalf;          // <= 296
            const float* src = E + ((size_t)n * NC + arow) * D + kb;
            float4 q0 = *reinterpret_cast<const float4*>(src);
            v[0] = q0.x; v[1] = q0.y; v[2] = q0.z; v[3] = q0.w;
            if (kb + 4 < 300) {
                float4 q1 = *reinterpret_cast<const float4*>(src + 4);
                v[4] = q1.x; v[5] = q1.y; v[6] = q1.z; v[7] = q1.w;
            }
            #pragma unroll
            for (int j = 0; j < 8; ++j)
                if (kb + j >= 300) v[j] = 0.f;      // K zero-pad
        }
        split8(v, ah[s5], al[s5]);
    }

    __syncthreads();                                // lcnt ready
    const int L = lcnt[0] + lcnt[1];
    const int ntiles = (L + 31) >> 5;
    const float* Tn = T + (size_t)n * WIN * D;

    // ---- tiled score GEMM: 32 tokens per tile, waves split K, MFMA ----
    for (int t = 0; t < ntiles; ++t) {
        const int t0 = t * 32;
        __syncthreads();                            // Tl free for restage
        // stage T tile (f32) via DMA; pad cols / OOB rows sourced from zeroed ws
        {
            const int QR = KP / 4;                  // 77 quads per row
            for (int i = tid; i < 32 * QR; i += 256) {
                int row = i / QR;
                int col = (i - row * QR) * 4;
                int gr  = t0 + row;
                const float* src = (col < 300 && gr < WIN)
                                 ? (Tn + (size_t)gr * 300 + col) : zws;
                __builtin_amdgcn_global_load_lds(
                    (const __attribute__((address_space(1))) void*)src,
                    (__attribute__((address_space(3))) void*)(Tl + 4 * i),
                    16, 0, 0);
            }
        }
        __syncthreads();                            // DMA drained (vmcnt before barrier)

        // per-wave partial GEMM over its k-steps
        f32x16 c;
        #pragma unroll
        for (int r = 0; r < 16; ++r) c[r] = 0.f;
        #pragma unroll
        for (int s5 = 0; s5 < 5; ++s5) {
            int s = ks0 + s5;
            if (s < NKS) {
                // B layout: lane holds T[tok = l&31][kb .. kb+8)
                const float* p = Tl + arow * KP + 16 * s + khalf;
                float4 q0 = *reinterpret_cast<const float4*>(p);
                float4 q1 = *reinterpret_cast<const float4*>(p + 4);
                float v[8] = {q0.x, q0.y, q0.z, q0.w, q1.x, q1.y, q1.z, q1.w};
                short8 bh, bl;
                split8(v, bh, bl);
                c = __builtin_amdgcn_mfma_f32_32x32x16_bf16(ah[s5], bh, c, 0, 0, 0);
                c = __builtin_amdgcn_mfma_f32_32x32x16_bf16(ah[s5], bl, c, 0, 0, 0);
                c = __builtin_amdgcn_mfma_f32_32x32x16_bf16(al[s5], bh, c, 0, 0, 0);
            }
        }
        // waves 1-3 dump partials; C layout: col=l&31, rows (reg&3)+8*(reg>>2)+4*(l>>5)
        if (wv > 0) {
            #pragma unroll
            for (int q = 0; q < 4; ++q) {
                int rq = 2 * q + (lane >> 5);
                *reinterpret_cast<float4*>(&Cred[wv - 1][rq][arow][0]) =
                    make_float4(c[4 * q], c[4 * q + 1], c[4 * q + 2], c[4 * q + 3]);
            }
        }
        __syncthreads();                            // partials visible
        if (wv == 0) {
            #pragma unroll
            for (int w = 0; w < 3; ++w) {
                #pragma unroll
                for (int q = 0; q < 4; ++q) {
                    int rq = 2 * q + (lane >> 5);
                    float4 r4 = *reinterpret_cast<const float4*>(&Cred[w][rq][arow][0]);
                    c[4 * q]     += r4.x;
                    c[4 * q + 1] += r4.y;
                    c[4 * q + 2] += r4.z;
                    c[4 * q + 3] += r4.w;
                }
            }
            // mask candidate pad rows 30,31 (regs 14,15 of lanes >= 32)
            if (lane >= 32) { c[14] = -__builtin_inff(); c[15] = -__builtin_inff(); }
            float m = c[0];
            #pragma unroll
            for (int r = 1; r < 16; ++r) m = fmaxf(m, c[r]);
            m = fmaxf(m, __shfl_xor(m, 32));        // combine row halves
            if (lane < 32 && t0 + (int)(lane) < L) ts[t0 + lane] = m;
        }
    }
    __syncthreads();                                // ts complete

    // ---- top-25 (wave 0, lower-index tie-break) + double-normalized softmax ----
    if (tid < 64) {
        float va = ts[tid];
        float vb = (tid + 64 < WIN) ? ts[tid + 64] : -__builtin_inff();
        float mx = 0.f;
        for (int t = 0; t < TOPK; ++t) {
            float v0; int i0;
            if (vb > va) { v0 = vb; i0 = tid + 64; } else { v0 = va; i0 = tid; }
            #pragma unroll
            for (int s = 32; s >= 1; s >>= 1) {
                float ov = __shfl_xor(v0, s);
                int   oi = __shfl_xor(i0, s);
                if (ov > v0 || (ov == v0 && oi < i0)) { v0 = ov; i0 = oi; }
            }
            if (t == 0) mx = v0;
            if (tid == 0) { bscore[t] = v0; bidx[t] = i0; }
            if (i0 == tid) va = -__builtin_inff();
            else if (i0 == tid + 64) vb = -__builtin_inff();
        }
        float sc = (tid < TOPK) ? bscore[tid] : 0.f;
        float p  = (tid < TOPK) ? expf(sc - mx) : 0.f;
        float s1 = p;
        #pragma unroll
        for (int s = 32; s >= 1; s >>= 1) s1 += __shfl_xor(s1, s);
        p = p / s1;
        float s2 = p;   // reference renormalizes a second time
        #pragma unroll
        for (int s = 32; s >= 1; s >>= 1) s2 += __shfl_xor(s2, s);
        p = p / s2;
        if (tid < TOPK) bprob[tid] = p;
    }
    __syncthreads();

    // ---- fcs: probability-weighted sum of best tokens (rows L2/L3-hot) ----
    float4 fc[10];
    #pragma unroll
    for (int j = 0; j < 10; ++j) fc[j] = make_float4(0.f, 0.f, 0.f, 0.f);
    for (int t = 0; t < TOPK; ++t) {
        const float p = bprob[t];
        const float* Trow = Tn + (size_t)bidx[t] * D + d0;
        float4 tt[10];
        #pragma unroll
        for (int j = 0; j < 5; ++j)
            tt[j] = *reinterpret_cast<const float4*>(Trow + 4 * j);
        if (full) {
            #pragma unroll
            for (int j = 5; j < 10; ++j)
                tt[j] = *reinterpret_cast<const float4*>(Trow + 4 * j);
        }
        #pragma unroll
        for (int j = 0; j < 5; ++j) {
            fc[j].x += p * tt[j].x; fc[j].y += p * tt[j].y;
            fc[j].z += p * tt[j].z; fc[j].w += p * tt[j].w;
        }
        if (full) {
            #pragma unroll
            for (int j = 5; j < 10; ++j) {
                fc[j].x += p * tt[j].x; fc[j].y += p * tt[j].y;
                fc[j].z += p * tt[j].z; fc[j].w += p * tt[j].w;
            }
        }
    }

    // ---- vals[c] = sum_d E[c,d] * B1[d] * fcs[d] ----
    const int cg = tid & 31;
    const bool cok = (cg < NC);
    float acc2 = 0.f;
    {
        const float* Erow = E + ((size_t)n * NC + (cok ? cg : 0)) * D + d0;
        float4 ev[10], bv[10];
        #pragma unroll
        for (int j = 0; j < 5; ++j) {
            ev[j] = *reinterpret_cast<const float4*>(Erow + 4 * j);
            bv[j] = *reinterpret_cast<const float4*>(B1 + d0 + 4 * j);
        }
        if (full) {
            #pragma unroll
            for (int j = 5; j < 10; ++j) {
                ev[j] = *reinterpret_cast<const float4*>(Erow + 4 * j);
                bv[j] = *reinterpret_cast<const float4*>(B1 + d0 + 4 * j);
            }
        } else {
            #pragma unroll
            for (int j = 5; j < 10; ++j) {
                ev[j] = make_float4(0.f, 0.f, 0.f, 0.f);
                bv[j] = make_float4(0.f, 0.f, 0.f, 0.f);
            }
        }
        #pragma unroll
        for (int j = 0; j < 10; ++j) {
            acc2 += ev[j].x * bv[j].x * fc[j].x + ev[j].y * bv[j].y * fc[j].y
                  + ev[j].z * bv[j].z * fc[j].z + ev[j].w * bv[j].w * fc[j].w;
        }
    }
    if (!cok) acc2 = 0.f;
    acc2 += __shfl_xor(acc2, 32);
    if (lane < 32) vred[wv][cg] = acc2;
    __syncthreads();
    if (tid < NC) {
        out[(size_t)n * NC + tid] =
            vred[0][tid] + vred[1][tid] + vred[2][tid] + vred[3][tid];
    }
}

extern "C" void kernel_launch(void* const* d_in, const int* in_sizes, int n_in,
                              void* d_out, int out_size, void* d_ws, size_t ws_size,
                              hipStream_t stream)
{
    const float* E  = (const float*)d_in[0];
    const float* T  = (const float*)d_in[1];
    const void*  M  = d_in[2];
    const float* B1 = (const float*)d_in[3];
    const float* B2 = (const float*)d_in[4];
    float* out = (float*)d_out;
    const int n = in_sizes[0] / (NC * D);   // number of mentions
    hipMemsetAsync(d_ws, 0, 64, stream);    // zero source for K-pad DMA reads
    fused_mention_kernel<<<n, 256, 0, stream>>>(E, T, M, B1, B2,
                                                (const float*)d_ws, out);
}

// Round 7
// 460.663 us; speedup vs baseline: 1.5587x; 1.1976x over previous
//
#include <hip/hip_runtime.h>
#include <math.h>

#define NC    30
#define D     300
#define WIN   100
#define TOPK  25
#define NEGV  -1e10f
#define NKS   19           // 19*16 = 304 >= 300

typedef __attribute__((ext_vector_type(8)))  short short8;
typedef __attribute__((ext_vector_type(16))) float f32x16;

__device__ inline unsigned short bftrunc(float f) {
    return (unsigned short)(__builtin_bit_cast(unsigned int, f) >> 16);
}
__device__ inline float bfval(unsigned short b) {
    return __builtin_bit_cast(float, (unsigned int)b << 16);
}
// split 8 f32 into bf16 hi/lo planes (a ~= hi + lo)
__device__ inline void split8(const float* v, short8& hi, short8& lo) {
    #pragma unroll
    for (int j = 0; j < 8; ++j) {
        unsigned short hb = bftrunc(v[j]);
        float lf = v[j] - bfval(hb);
        hi[j] = (short)hb;
        lo[j] = (short)bftrunc(lf);
    }
}

__global__ __launch_bounds__(256, 2)
void fused_mention_kernel(const float* __restrict__ E,
                          const float* __restrict__ T,
                          const void*  __restrict__ maskp,
                          const float* __restrict__ B1,
                          const float* __restrict__ B2,
                          float* __restrict__ out)
{
    const int n     = blockIdx.x;
    const int tid   = threadIdx.x;
    const int wv    = tid >> 6;
    const int lane  = tid & 63;
    const int arow  = lane & 31;          // A row (candidate) / B col (token)
    const int khalf = (lane >> 5) * 8;
    const int ks0   = wv * 5;             // K-split: waves 0-2: 5 steps, wave 3: 4

    __shared__ float Cred[3][8][32][4];   // 12.3 KB cross-wave C partials
    __shared__ __align__(16) float fcsL[D];
    __shared__ float ts[WIN];
    __shared__ float bscore[TOPK];
    __shared__ int   bidx[TOPK];
    __shared__ float bprob[TOPK];
    __shared__ float vred[4][32];
    __shared__ int   mmode;
    __shared__ int   lcnt[2];

    // ---- mask dtype detect + ts init ----
    if (tid == 0) mmode = 0;
    if (tid < WIN) ts[tid] = NEGV;
    __syncthreads();
    {
        const unsigned char* mb = (const unsigned char*)maskp;
        int found = 0;
        for (int i = tid; i < 4096; i += 256)
            if ((i & 3) && mb[i]) found = 1;
        if (found) mmode = 1;
    }
    __syncthreads();

    // ---- valid-prefix length L via 2-wave ballot ----
    if (tid < 128) {
        int v = 0;
        if (tid < WIN) {
            if (mmode) v = ((const unsigned char*)maskp)[(size_t)n * WIN + tid] != 0;
            else       v = ((const int*)maskp)[(size_t)n * WIN + tid] != 0;
        }
        unsigned long long b = __ballot(v);
        if (lane == 0) lcnt[wv] = __popcll(b);
    }

    // ---- A-frags: E x B_diag2, f32 load then bf16 hi/lo split ----
    float av[5][8];
    #pragma unroll
    for (int s5 = 0; s5 < 5; ++s5) {
        #pragma unroll
        for (int j = 0; j < 8; ++j) av[s5][j] = 0.f;
        const int s = ks0 + s5;
        if (s < NKS && arow < NC) {
            const int kb = 16 * s + khalf;                    // <= 296
            const float* src = E + ((size_t)n * NC + arow) * D + kb;
            float4 q0 = *reinterpret_cast<const float4*>(src);
            float4 b0 = *reinterpret_cast<const float4*>(B2 + kb);
            av[s5][0] = q0.x * b0.x; av[s5][1] = q0.y * b0.y;
            av[s5][2] = q0.z * b0.z; av[s5][3] = q0.w * b0.w;
            if (kb + 8 <= 300) {
                float4 q1 = *reinterpret_cast<const float4*>(src + 4);
                float4 b1 = *reinterpret_cast<const float4*>(B2 + kb + 4);
                av[s5][4] = q1.x * b1.x; av[s5][5] = q1.y * b1.y;
                av[s5][6] = q1.z * b1.z; av[s5][7] = q1.w * b1.w;
            }
        }
    }
    short8 ah[5], al[5];
    #pragma unroll
    for (int s5 = 0; s5 < 5; ++s5) split8(av[s5], ah[s5], al[s5]);

    __syncthreads();                                  // lcnt ready
    const int L = lcnt[0] + lcnt[1];
    const int ntiles = (L + 31) >> 5;
    const float* Tn = T + (size_t)n * WIN * D;

    // ---- score GEMM: B-frags gathered DIRECTLY from global, zero barriers ----
    f32x16 c4[4];
    #pragma unroll
    for (int t = 0; t < 4; ++t)
        #pragma unroll
        for (int r = 0; r < 16; ++r) c4[t][r] = 0.f;

    #pragma unroll
    for (int t = 0; t < 4; ++t) {
        if (t < ntiles) {
            const float* bp = Tn + (size_t)min(t * 32 + arow, WIN - 1) * D;
            #pragma unroll
            for (int s5 = 0; s5 < 5; ++s5) {
                const int s = ks0 + s5;
                if (s < NKS) {
                    const int kb = 16 * s + khalf;
                    float v[8] = {0.f, 0.f, 0.f, 0.f, 0.f, 0.f, 0.f, 0.f};
                    float4 q0 = *reinterpret_cast<const float4*>(bp + kb);
                    v[0] = q0.x; v[1] = q0.y; v[2] = q0.z; v[3] = q0.w;
                    if (kb + 8 <= 300) {
                        float4 q1 = *reinterpret_cast<const float4*>(bp + kb + 4);
                        v[4] = q1.x; v[5] = q1.y; v[6] = q1.z; v[7] = q1.w;
                    }
                    short8 bh, bl;
                    split8(v, bh, bl);
                    c4[t] = __builtin_amdgcn_mfma_f32_32x32x16_bf16(ah[s5], bh, c4[t], 0, 0, 0);
                    c4[t] = __builtin_amdgcn_mfma_f32_32x32x16_bf16(al[s5], bh, c4[t], 0, 0, 0);
                    c4[t] = __builtin_amdgcn_mfma_f32_32x32x16_bf16(ah[s5], bl, c4[t], 0, 0, 0);
                }
            }
        }
    }

    // ---- end-phase: cross-wave reduce + token max, per tile ----
    #pragma unroll
    for (int t = 0; t < 4; ++t) {
        if (t < ntiles) {
            if (wv > 0) {
                #pragma unroll
                for (int q = 0; q < 4; ++q) {
                    const int rq = 2 * q + (lane >> 5);
                    *reinterpret_cast<float4*>(&Cred[wv - 1][rq][arow][0]) =
                        make_float4(c4[t][4 * q], c4[t][4 * q + 1],
                                    c4[t][4 * q + 2], c4[t][4 * q + 3]);
                }
            }
            __syncthreads();
            if (wv == 0) {
                #pragma unroll
                for (int w = 0; w < 3; ++w) {
                    #pragma unroll
                    for (int q = 0; q < 4; ++q) {
                        const int rq = 2 * q + (lane >> 5);
                        float4 r4 = *reinterpret_cast<const float4*>(&Cred[w][rq][arow][0]);
                        c4[t][4 * q]     += r4.x;
                        c4[t][4 * q + 1] += r4.y;
                        c4[t][4 * q + 2] += r4.z;
                        c4[t][4 * q + 3] += r4.w;
                    }
                }
                // mask candidate pad rows 30,31 (regs 14,15 of lanes >= 32)
                if (lane >= 32) { c4[t][14] = -__builtin_inff(); c4[t][15] = -__builtin_inff(); }
                float m = c4[t][0];
                #pragma unroll
                for (int r = 1; r < 16; ++r) m = fmaxf(m, c4[t][r]);
                m = fmaxf(m, __shfl_xor(m, 32));
                if (lane < 32 && t * 32 + arow < L) ts[t * 32 + arow] = m;
            }
            __syncthreads();
        }
    }

    // ---- top-25 (wave 0, lower-index tie-break) + double-normalized softmax ----
    if (tid < 64) {
        float va = ts[tid];
        float vb = (tid + 64 < WIN) ? ts[tid + 64] : -__builtin_inff();
        float mx = 0.f;
        for (int t = 0; t < TOPK; ++t) {
            float v0; int i0;
            if (vb > va) { v0 = vb; i0 = tid + 64; } else { v0 = va; i0 = tid; }
            #pragma unroll
            for (int s = 32; s >= 1; s >>= 1) {
                float ov = __shfl_xor(v0, s);
                int   oi = __shfl_xor(i0, s);
                if (ov > v0 || (ov == v0 && oi < i0)) { v0 = ov; i0 = oi; }
            }
            if (t == 0) mx = v0;
            if (tid == 0) { bscore[t] = v0; bidx[t] = i0; }
            if (i0 == tid) va = -__builtin_inff();
            else if (i0 == tid + 64) vb = -__builtin_inff();
        }
        float sc = (tid < TOPK) ? bscore[tid] : 0.f;
        float p  = (tid < TOPK) ? expf(sc - mx) : 0.f;
        float s1 = p;
        #pragma unroll
        for (int s = 32; s >= 1; s >>= 1) s1 += __shfl_xor(s1, s);
        p = p / s1;
        float s2 = p;   // reference renormalizes a second time
        #pragma unroll
        for (int s = 32; s >= 1; s >>= 1) s2 += __shfl_xor(s2, s);
        p = p / s2;
        if (tid < TOPK) bprob[tid] = p;
    }
    __syncthreads();

    // ---- fcs: dim-parallel weighted sum, coalesced global reads (L2-hot) ----
    for (int d = tid; d < D; d += 256) {
        float acc = 0.f;
        #pragma unroll
        for (int t = 0; t < TOPK; ++t)
            acc += bprob[t] * Tn[(size_t)bidx[t] * D + d];
        fcsL[d] = acc;
    }
    __syncthreads();

    // ---- vals[c] = sum_d E[c,d] * B1[d] * fcs[d] ----
    {
        const int dg = tid >> 5;
        const int d0 = dg * 40;
        const bool full = (dg < 7);
        const int cg = arow;
        const bool cok = (cg < NC);
        float acc2 = 0.f;
        const float* Erow = E + ((size_t)n * NC + (cok ? cg : 0)) * D + d0;
        #pragma unroll
        for (int j = 0; j < 5; ++j) {
            float4 ev = *reinterpret_cast<const float4*>(Erow + 4 * j);
            float4 bv = *reinterpret_cast<const float4*>(B1 + d0 + 4 * j);
            float4 fv = *reinterpret_cast<const float4*>(fcsL + d0 + 4 * j);
            acc2 += ev.x * bv.x * fv.x + ev.y * bv.y * fv.y
                  + ev.z * bv.z * fv.z + ev.w * bv.w * fv.w;
        }
        if (full) {
            #pragma unroll
            for (int j = 5; j < 10; ++j) {
                float4 ev = *reinterpret_cast<const float4*>(Erow + 4 * j);
                float4 bv = *reinterpret_cast<const float4*>(B1 + d0 + 4 * j);
                float4 fv = *reinterpret_cast<const float4*>(fcsL + d0 + 4 * j);
                acc2 += ev.x * bv.x * fv.x + ev.y * bv.y * fv.y
                      + ev.z * bv.z * fv.z + ev.w * bv.w * fv.w;
            }
        }
        if (!cok) acc2 = 0.f;
        acc2 += __shfl_xor(acc2, 32);
        if (lane < 32) vred[wv][cg] = acc2;
    }
    __syncthreads();
    if (tid < NC) {
        out[(size_t)n * NC + tid] =
            vred[0][tid] + vred[1][tid] + vred[2][tid] + vred[3][tid];
    }
}

extern "C" void kernel_launch(void* const* d_in, const int* in_sizes, int n_in,
                              void* d_out, int out_size, void* d_ws, size_t ws_size,
                              hipStream_t stream)
{
    const float* E  = (const float*)d_in[0];
    const float* T  = (const float*)d_in[1];
    const void*  M  = d_in[2];
    const float* B1 = (const float*)d_in[3];
    const float* B2 = (const float*)d_in[4];
    float* out = (float*)d_out;
    const int n = in_sizes[0] / (NC * D);   // number of mentions
    fused_mention_kernel<<<n, 256, 0, stream>>>(E, T, M, B1, B2, out);
}

// Round 8
// 340.169 us; speedup vs baseline: 2.1108x; 1.3542x over previous
//
#include <hip/hip_runtime.h>
#include <math.h>

#define NC    30
#define D     300
#define WIN   100
#define TOPK  25
#define NEGV  -1e10f
#define NKS   19           // 19*16 = 304 >= 300
#define AST   312          // A-plane LDS row stride in shorts (624 B, 16B-aligned)

typedef __attribute__((ext_vector_type(8)))  short short8;
typedef __attribute__((ext_vector_type(16))) float f32x16;

__device__ inline unsigned short bftrunc(float f) {
    return (unsigned short)(__builtin_bit_cast(unsigned int, f) >> 16);
}
__device__ inline float bfval(unsigned short b) {
    return __builtin_bit_cast(float, (unsigned int)b << 16);
}
__device__ inline void split8(const float* v, short8& hi, short8& lo) {
    #pragma unroll
    for (int j = 0; j < 8; ++j) {
        unsigned short hb = bftrunc(v[j]);
        float lf = v[j] - bfval(hb);
        hi[j] = (short)hb;
        lo[j] = (short)bftrunc(lf);
    }
}

__global__ __launch_bounds__(256, 3)
void fused_mention_kernel(const float* __restrict__ E,
                          const float* __restrict__ T,
                          const void*  __restrict__ maskp,
                          const float* __restrict__ B1,
                          const float* __restrict__ B2,
                          float* __restrict__ out)
{
    const int n     = blockIdx.x;
    const int tid   = threadIdx.x;
    const int wv    = tid >> 6;
    const int lane  = tid & 63;
    const int arow  = lane & 31;          // candidate row (A) / token col (B)
    const int khalf = (lane >> 5) * 8;

    __shared__ __align__(16) short Ah[NC * AST];   // 18.7 KB bf16-hi of E*B2
    __shared__ __align__(16) short Al[NC * AST];   // 18.7 KB bf16-lo
    __shared__ __align__(16) float fcsL[D];
    __shared__ float ts[WIN];
    __shared__ float bscore[TOPK];
    __shared__ int   bidx[TOPK];
    __shared__ float bprob[TOPK];
    __shared__ float vred[4][32];
    __shared__ int   mmode;
    __shared__ int   lcnt[2];

    // ---- mask dtype detect + ts init ----
    if (tid == 0) mmode = 0;
    if (tid < WIN) ts[tid] = NEGV;
    __syncthreads();
    {
        const unsigned char* mb = (const unsigned char*)maskp;
        int found = 0;
        for (int i = tid; i < 4096; i += 256)
            if ((i & 3) && mb[i]) found = 1;
        if (found) mmode = 1;
    }
    __syncthreads();

    // ---- valid-prefix length L via 2-wave ballot ----
    if (tid < 128) {
        int v = 0;
        if (tid < WIN) {
            if (mmode) v = ((const unsigned char*)maskp)[(size_t)n * WIN + tid] != 0;
            else       v = ((const int*)maskp)[(size_t)n * WIN + tid] != 0;
        }
        unsigned long long b = __ballot(v);
        if (lane == 0) lcnt[wv] = __popcll(b);
    }

    // ---- stage A = E * B_diag2 into LDS as bf16 hi/lo (30 rows x 304 cols) ----
    {
        // 38 8-col chunks per row cover cols 0..303 (zero-padded past 299)
        for (int i = tid; i < NC * 38; i += 256) {
            const int row = i / 38;
            const int c8  = i - row * 38;
            const int col = c8 * 8;
            const float* src = E + ((size_t)n * NC + row) * D + col;
            float v[8];
            float4 q0 = *reinterpret_cast<const float4*>(src);
            float4 b0 = *reinterpret_cast<const float4*>(B2 + col);
            v[0] = q0.x * b0.x; v[1] = q0.y * b0.y;
            v[2] = q0.z * b0.z; v[3] = q0.w * b0.w;
            if (c8 < 37) {
                float4 q1 = *reinterpret_cast<const float4*>(src + 4);
                float4 b1 = *reinterpret_cast<const float4*>(B2 + col + 4);
                v[4] = q1.x * b1.x; v[5] = q1.y * b1.y;
                v[6] = q1.z * b1.z; v[7] = q1.w * b1.w;
            } else {
                v[4] = v[5] = v[6] = v[7] = 0.f;   // cols 300..303 zero
            }
            short8 hi, lo;
            split8(v, hi, lo);
            *reinterpret_cast<short8*>(Ah + row * AST + col) = hi;
            *reinterpret_cast<short8*>(Al + row * AST + col) = lo;
        }
    }
    __syncthreads();                                  // A staged + lcnt ready
    const int L = lcnt[0] + lcnt[1];
    const int ntiles = (L + 31) >> 5;
    const float* Tn = T + (size_t)n * WIN * D;

    // ---- score GEMM: wave wv owns tile wv; B gathered from global ----
    if (wv < ntiles) {
        const int t0 = wv * 32;
        const float* bp = Tn + (size_t)min(t0 + arow, WIN - 1) * D;
        const int aoff = min(arow, NC - 1) * AST + khalf;   // rows 30,31 clamp (masked)
        f32x16 c;
        #pragma unroll
        for (int r = 0; r < 16; ++r) c[r] = 0.f;
        #pragma unroll
        for (int s = 0; s < NKS; ++s) {
            const int kb = 16 * s + khalf;
            // A frags from LDS
            short8 ah = *reinterpret_cast<const short8*>(Ah + aoff + 16 * s);
            short8 al = *reinterpret_cast<const short8*>(Al + aoff + 16 * s);
            // B frag from global
            float v[8] = {0.f, 0.f, 0.f, 0.f, 0.f, 0.f, 0.f, 0.f};
            float4 q0 = *reinterpret_cast<const float4*>(bp + kb);
            v[0] = q0.x; v[1] = q0.y; v[2] = q0.z; v[3] = q0.w;
            if (kb + 8 <= 300) {
                float4 q1 = *reinterpret_cast<const float4*>(bp + kb + 4);
                v[4] = q1.x; v[5] = q1.y; v[6] = q1.z; v[7] = q1.w;
            }
            short8 bh, bl;
            split8(v, bh, bl);
            c = __builtin_amdgcn_mfma_f32_32x32x16_bf16(ah, bh, c, 0, 0, 0);
            c = __builtin_amdgcn_mfma_f32_32x32x16_bf16(al, bh, c, 0, 0, 0);
            c = __builtin_amdgcn_mfma_f32_32x32x16_bf16(ah, bl, c, 0, 0, 0);
        }
        // wave-local token max; mask pad rows 30,31 (regs 14,15 of lanes >= 32)
        if (lane >= 32) { c[14] = -__builtin_inff(); c[15] = -__builtin_inff(); }
        float m = c[0];
        #pragma unroll
        for (int r = 1; r < 16; ++r) m = fmaxf(m, c[r]);
        m = fmaxf(m, __shfl_xor(m, 32));
        if (lane < 32 && t0 + arow < L) ts[t0 + arow] = m;
    }
    __syncthreads();                                  // ts complete

    // ---- top-25 (wave 0, lower-index tie-break) + double-normalized softmax ----
    if (tid < 64) {
        float va = ts[tid];
        float vb = (tid + 64 < WIN) ? ts[tid + 64] : -__builtin_inff();
        float mx = 0.f;
        for (int t = 0; t < TOPK; ++t) {
            float v0; int i0;
            if (vb > va) { v0 = vb; i0 = tid + 64; } else { v0 = va; i0 = tid; }
            #pragma unroll
            for (int s = 32; s >= 1; s >>= 1) {
                float ov = __shfl_xor(v0, s);
                int   oi = __shfl_xor(i0, s);
                if (ov > v0 || (ov == v0 && oi < i0)) { v0 = ov; i0 = oi; }
            }
            if (t == 0) mx = v0;
            if (tid == 0) { bscore[t] = v0; bidx[t] = i0; }
            if (i0 == tid) va = -__builtin_inff();
            else if (i0 == tid + 64) vb = -__builtin_inff();
        }
        float sc = (tid < TOPK) ? bscore[tid] : 0.f;
        float p  = (tid < TOPK) ? expf(sc - mx) : 0.f;
        float s1 = p;
        #pragma unroll
        for (int s = 32; s >= 1; s >>= 1) s1 += __shfl_xor(s1, s);
        p = p / s1;
        float s2 = p;   // reference renormalizes a second time
        #pragma unroll
        for (int s = 32; s >= 1; s >>= 1) s2 += __shfl_xor(s2, s);
        p = p / s2;
        if (tid < TOPK) bprob[tid] = p;
    }
    __syncthreads();

    // ---- fcs: dim-parallel weighted sum, coalesced global reads (L2-hot) ----
    for (int d = tid; d < D; d += 256) {
        float acc = 0.f;
        #pragma unroll
        for (int t = 0; t < TOPK; ++t)
            acc += bprob[t] * Tn[(size_t)bidx[t] * D + d];
        fcsL[d] = acc;
    }
    __syncthreads();

    // ---- vals[c] = sum_d E[c,d] * B1[d] * fcs[d] ----
    {
        const int dg = tid >> 5;
        const int d0 = dg * 40;
        const bool full = (dg < 7);
        const int cg = arow;
        const bool cok = (cg < NC);
        float acc2 = 0.f;
        const float* Erow = E + ((size_t)n * NC + (cok ? cg : 0)) * D + d0;
        #pragma unroll
        for (int j = 0; j < 5; ++j) {
            float4 ev = *reinterpret_cast<const float4*>(Erow + 4 * j);
            float4 bv = *reinterpret_cast<const float4*>(B1 + d0 + 4 * j);
            float4 fv = *reinterpret_cast<const float4*>(fcsL + d0 + 4 * j);
            acc2 += ev.x * bv.x * fv.x + ev.y * bv.y * fv.y
                  + ev.z * bv.z * fv.z + ev.w * bv.w * fv.w;
        }
        if (full) {
            #pragma unroll
            for (int j = 5; j < 10; ++j) {
                float4 ev = *reinterpret_cast<const float4*>(Erow + 4 * j);
                float4 bv = *reinterpret_cast<const float4*>(B1 + d0 + 4 * j);
                float4 fv = *reinterpret_cast<const float4*>(fcsL + d0 + 4 * j);
                acc2 += ev.x * bv.x * fv.x + ev.y * bv.y * fv.y
                      + ev.z * bv.z * fv.z + ev.w * bv.w * fv.w;
            }
        }
        if (!cok) acc2 = 0.f;
        acc2 += __shfl_xor(acc2, 32);
        if (lane < 32) vred[wv][cg] = acc2;
    }
    __syncthreads();
    if (tid < NC) {
        out[(size_t)n * NC + tid] =
            vred[0][tid] + vred[1][tid] + vred[2][tid] + vred[3][tid];
    }
}

extern "C" void kernel_launch(void* const* d_in, const int* in_sizes, int n_in,
                              void* d_out, int out_size, void* d_ws, size_t ws_size,
                              hipStream_t stream)
{
    const float* E  = (const float*)d_in[0];
    const float* T  = (const float*)d_in[1];
    const void*  M  = d_in[2];
    const float* B1 = (const float*)d_in[3];
    const float* B2 = (const float*)d_in[4];
    float* out = (float*)d_out;
    const int n = in_sizes[0] / (NC * D);   // number of mentions
    fused_mention_kernel<<<n, 256, 0, stream>>>(E, T, M, B1, B2, out);
}